// Round 4
// baseline (373.616 us; speedup 1.0000x reference)
//
#include <hip/hip_runtime.h>
#include <hip/hip_bf16.h>

typedef __bf16 bf16_t;
typedef __attribute__((ext_vector_type(8))) __bf16 bf16x8;
typedef __attribute__((ext_vector_type(4))) float f32x4;

#define E_DIM 256
#define J_DIM 32
#define B_DIM 4096
#define M_DIM (B_DIM * J_DIM)
#define BM 64
#define BK 32
#define LDA 40   // bf16 state tile: BK + 8 pad (16B-aligned rows, banks spread)

// load 8 consecutive fp32, convert to bf16x8 (RNE)
__device__ inline bf16x8 cvt8(const float* __restrict__ p) {
    f32x4 a = *(const f32x4*)p;
    f32x4 b = *(const f32x4*)(p + 4);
    bf16x8 r;
    r[0] = (bf16_t)a[0]; r[1] = (bf16_t)a[1]; r[2] = (bf16_t)a[2]; r[3] = (bf16_t)a[3];
    r[4] = (bf16_t)b[0]; r[5] = (bf16_t)b[1]; r[6] = (bf16_t)b[2]; r[7] = (bf16_t)b[3];
    return r;
}

// One fused prep kernel, 320 blocks:
//   blocks   0..255 : wx[b0..b0+16][:] = x@W^T   and  xk[b0..b0+16][:] = x@keys^T
//   blocks 256..287 : vkb[j][:] = bias + keys_j@V^T
//   blocks 288..319 : Ub = bf16(U)   (one-time convert so main can DMA-stage U)
__global__ __launch_bounds__(256) void prep_kernel(
    const float* __restrict__ x, const float* __restrict__ keys,
    const float* __restrict__ U, const float* __restrict__ V,
    const float* __restrict__ W, const float* __restrict__ bias,
    float* __restrict__ wx, float* __restrict__ xk,
    float* __restrict__ vkb, bf16_t* __restrict__ Ub) {
    int bid = blockIdx.x, tid = threadIdx.x;
    if (bid < 256) {
        __shared__ __align__(16) float sx[16][E_DIM + 4];  // row = 1040 B (16B-mult)
        int b0 = bid * 16;
        {   // stage 16 x-rows
            int r = tid >> 4, c = tid & 15;
            const float* xp = x + (size_t)(b0 + r) * E_DIM + c * 16;
#pragma unroll
            for (int q = 0; q < 4; ++q)
                *(f32x4*)(&sx[r][c * 16 + q * 4]) = *(const f32x4*)(xp + q * 4);
        }
        __syncthreads();
        // wx: thread owns column f = tid, loops 16 b's
        int f = tid;
        float acc[16];
#pragma unroll
        for (int b = 0; b < 16; ++b) acc[b] = 0.f;
        for (int e0 = 0; e0 < E_DIM; e0 += 8) {
            f32x4 w0 = *(const f32x4*)(W + (size_t)f * E_DIM + e0);
            f32x4 w1 = *(const f32x4*)(W + (size_t)f * E_DIM + e0 + 4);
#pragma unroll
            for (int b = 0; b < 16; ++b) {
                float a = acc[b];
#pragma unroll
                for (int i = 0; i < 4; ++i) a = fmaf(w0[i], sx[b][e0 + i], a);
#pragma unroll
                for (int i = 0; i < 4; ++i) a = fmaf(w1[i], sx[b][e0 + 4 + i], a);
                acc[b] = a;
            }
        }
#pragma unroll
        for (int b = 0; b < 16; ++b) wx[(size_t)(b0 + b) * E_DIM + f] = acc[b];
        // xk: thread = (j = tid&31, bg = tid>>5), 2 b's per thread
        int j = tid & 31, bg = tid >> 5;
        float a0 = 0.f, a1 = 0.f;
        for (int e = 0; e < E_DIM; e += 4) {
            f32x4 kv = *(const f32x4*)(keys + (size_t)j * E_DIM + e);
            f32x4 x0 = *(const f32x4*)(&sx[bg * 2][e]);
            f32x4 x1 = *(const f32x4*)(&sx[bg * 2 + 1][e]);
#pragma unroll
            for (int i = 0; i < 4; ++i) { a0 = fmaf(kv[i], x0[i], a0); a1 = fmaf(kv[i], x1[i], a1); }
        }
        xk[(size_t)(b0 + bg * 2) * J_DIM + j] = a0;
        xk[(size_t)(b0 + bg * 2 + 1) * J_DIM + j] = a1;
    } else if (bid < 288) {
        // vkb for j = bid-256
        int j = bid - 256, f = tid;
        __shared__ float sk[E_DIM];
        sk[f] = keys[(size_t)j * E_DIM + f];
        __syncthreads();
        float acc = bias[f];
        for (int e = 0; e < E_DIM; e += 4) {
            f32x4 vv = *(const f32x4*)(V + (size_t)f * E_DIM + e);
#pragma unroll
            for (int i = 0; i < 4; ++i) acc = fmaf(vv[i], sk[e + i], acc);
        }
        vkb[(size_t)j * E_DIM + f] = acc;
    } else {
        // Ub convert: 32 blocks x 256 threads x 8 elements = 65536
        size_t idx = ((size_t)(bid - 288) * 256 + tid) * 8;
        *(bf16x8*)(Ub + idx) = cvt8(U + idx);
    }
}

// main: cand = s@U^T + wx[b] + vkb[j]; gate = sigmoid(<x,s>_fp32 + xk);
//       out = normalize(s + gate*relu(cand))
// U staged via global_load_lds (async DMA, bf16, no VGPR round-trip).
// gate dot computed in fp32 from the state staging registers.
__global__ __launch_bounds__(256) void memcell_kernel(
    const float* __restrict__ x, const float* __restrict__ state,
    const bf16_t* __restrict__ Ub, const float* __restrict__ wx,
    const float* __restrict__ xk, const float* __restrict__ vkb,
    float* __restrict__ out) {
    __shared__ __align__(16) bf16_t sA[BM][LDA];     // state tile, bf16
    __shared__ __align__(16) bf16_t sB[E_DIM][BK];   // U tile, unpadded (DMA layout)
    __shared__ __align__(16) float sXf[2][E_DIM];    // fp32 x rows (gate dot)
    int tid = threadIdx.x;
    int w = tid >> 6, lane = tid & 63, quad = lane >> 4, l15 = lane & 15;
    int m0 = blockIdx.x * BM;
    int b0 = m0 >> 5;                       // block covers b0, b0+1
    f32x4 acc[16];
#pragma unroll
    for (int nt = 0; nt < 16; ++nt)
#pragma unroll
        for (int r = 0; r < 4; ++r) acc[nt][r] = 0.f;
    if (tid < 64) {                          // stage the 2 fp32 x-rows
        int bb = tid >> 5, p = tid & 31;
        *(f32x4*)(&sXf[bb][p * 8]) = *(const f32x4*)(x + (size_t)(b0 + bb) * E_DIM + p * 8);
        *(f32x4*)(&sXf[bb][p * 8 + 4]) = *(const f32x4*)(x + (size_t)(b0 + bb) * E_DIM + p * 8 + 4);
    }
    int arow = tid >> 2, akk = (tid & 3) * 8;   // staging assignment: 4 threads/row
    int bbs = arow >> 5;                        // which x-row this state row uses
    float gpart = 0.f;
    for (int kc = 0; kc < 8; ++kc) {
        int k0 = kc * BK;
        __syncthreads();   // prev tiles consumed (also makes sXf visible, kc=0)
        // --- async DMA: U tile (256 x 32 bf16) into sB; wave w fills rows w*64..w*64+63
#pragma unroll
        for (int is = 0; is < 4; ++is) {
            int row = w * 64 + is * 16 + (lane >> 2);
            const bf16_t* gp = Ub + (size_t)row * E_DIM + k0 + (lane & 3) * 8;
            __builtin_amdgcn_global_load_lds(
                (const __attribute__((address_space(1))) void*)gp,
                (__attribute__((address_space(3))) void*)(&sB[w * 64 + is * 16][0]),
                16, 0, 0);
        }
        // --- state tile: global -> regs (gate-dot fp32 partial) -> bf16 LDS
        {
            const float* sp = state + (size_t)(m0 + arow) * E_DIM + k0 + akk;
            f32x4 a = *(const f32x4*)sp;
            f32x4 b = *(const f32x4*)(sp + 4);
#pragma unroll
            for (int i = 0; i < 4; ++i) gpart = fmaf(a[i], sXf[bbs][k0 + akk + i], gpart);
#pragma unroll
            for (int i = 0; i < 4; ++i) gpart = fmaf(b[i], sXf[bbs][k0 + akk + 4 + i], gpart);
            bf16x8 r;
            r[0] = (bf16_t)a[0]; r[1] = (bf16_t)a[1]; r[2] = (bf16_t)a[2]; r[3] = (bf16_t)a[3];
            r[4] = (bf16_t)b[0]; r[5] = (bf16_t)b[1]; r[6] = (bf16_t)b[2]; r[7] = (bf16_t)b[3];
            *(bf16x8*)(&sA[arow][akk]) = r;
        }
        __syncthreads();   // drains DMA (vmcnt0) + LDS writes
        // --- MFMA: A-frag row = w*16+l15, k = quad*8
        bf16x8 af = *(const bf16x8*)(&sA[w * 16 + l15][quad * 8]);
#pragma unroll
        for (int nt = 0; nt < 16; ++nt) {
            bf16x8 bfr = *(const bf16x8*)(&sB[nt * 16 + l15][quad * 8]);
            acc[nt] = __builtin_amdgcn_mfma_f32_16x16x32_bf16(af, bfr, acc[nt], 0, 0, 0);
        }
    }
    // gate: reduce fp32 partials over the 4 staging threads of each row
    gpart += __shfl_xor(gpart, 1);
    gpart += __shfl_xor(gpart, 2);
    int grow = m0 + arow;
    float garg = gpart + xk[(size_t)(grow >> 5) * J_DIM + (grow & 31)];
    float gv = 1.f / (1.f + expf(-garg));
    // epilogue lane (quad,l15) needs gate for rows quad*4+r; holder lane = (quad*4+r)*4
    float gate[4];
#pragma unroll
    for (int r = 0; r < 4; ++r) gate[r] = __shfl(gv, quad * 16 + r * 4);
    // epilogue: C/D layout row = quad*4+r, col = nt*16+l15
    float sumsq[4] = {0.f, 0.f, 0.f, 0.f};
    int bw = b0 + (w >> 1);
    const float* wxrow = wx + (size_t)bw * E_DIM;
#pragma unroll
    for (int nt = 0; nt < 16; ++nt) {
        int f = nt * 16 + l15;
        float wxf = wxrow[f];
#pragma unroll
        for (int r = 0; r < 4; ++r) {
            int rl = quad * 4 + r;
            int jidx = (w & 1) * 16 + rl;
            float c = acc[nt][r] + wxf + vkb[(size_t)jidx * E_DIM + f];
            c = fmaxf(c, 0.f);
            float sv = state[(size_t)(m0 + w * 16 + rl) * E_DIM + f]; // L2-hot re-read
            float t = fmaf(gate[r], c, sv);
            acc[nt][r] = t;
            sumsq[r] += t * t;
        }
    }
    float rn[4];
#pragma unroll
    for (int r = 0; r < 4; ++r) {
        float s2 = sumsq[r];
        s2 += __shfl_xor(s2, 1);
        s2 += __shfl_xor(s2, 2);
        s2 += __shfl_xor(s2, 4);
        s2 += __shfl_xor(s2, 8);
        rn[r] = 1.f / (sqrtf(s2) + 1e-8f);
    }
#pragma unroll
    for (int nt = 0; nt < 16; ++nt)
#pragma unroll
        for (int r = 0; r < 4; ++r)
            out[(size_t)(m0 + w * 16 + quad * 4 + r) * E_DIM + nt * 16 + l15] =
                acc[nt][r] * rn[r];
}

extern "C" void kernel_launch(void* const* d_in, const int* in_sizes, int n_in,
                              void* d_out, int out_size, void* d_ws, size_t ws_size,
                              hipStream_t stream) {
    const float* x     = (const float*)d_in[0];
    const float* state = (const float*)d_in[1];
    const float* keys  = (const float*)d_in[2];
    const float* U     = (const float*)d_in[3];
    const float* V     = (const float*)d_in[4];
    const float* W     = (const float*)d_in[5];
    const float* bias  = (const float*)d_in[6];
    float* out = (float*)d_out;

    float* wsf = (float*)d_ws;
    float*  wx  = wsf;                                            // 4 MB
    float*  xk  = wsf + (size_t)B_DIM * E_DIM;                    // 512 KB
    float*  vkb = xk + (size_t)B_DIM * J_DIM;                     // 32 KB
    bf16_t* Ub  = (bf16_t*)(vkb + (size_t)J_DIM * E_DIM);         // 128 KB

    prep_kernel<<<320, 256, 0, stream>>>(x, keys, U, V, W, bias, wx, xk, vkb, Ub);
    memcell_kernel<<<M_DIM / BM, 256, 0, stream>>>(x, state, Ub, wx, xk, vkb, out);
}